// Round 9
// baseline (172.072 us; speedup 1.0000x reference)
//
#include <hip/hip_runtime.h>

// ---------------- problem constants ----------------
#define MAX_IN   1024
#define MAX_OUT  4096
#define LOW_RANK 64
#define N_ARCH   16
#define HYP_HID  128
#define BATCH_M  8192   // 4 * 2048

typedef __attribute__((ext_vector_type(8))) short short8;   // 8 x bf16
typedef __attribute__((ext_vector_type(4))) float f32x4;

// round-to-nearest-even fp32 -> bf16
__device__ __forceinline__ unsigned short f2bf(float f) {
  union { float f; unsigned int u; } c; c.f = f;
  unsigned int r = c.u + 0x7fffu + ((c.u >> 16) & 1u);
  return (unsigned short)(r >> 16);
}

__device__ __forceinline__ void gload16(const unsigned short* g, unsigned short* l) {
  __builtin_amdgcn_global_load_lds(
      (const __attribute__((address_space(1))) unsigned int*)(g),
      (__attribute__((address_space(3))) unsigned int*)(l), 16, 0, 0);
}

// ---------------- kernel 1: X fp32 -> bf16 ----------------
__global__ __launch_bounds__(256) void convert_x(const float* __restrict__ in,
                                                 unsigned short* __restrict__ out) {
  size_t i = (size_t)blockIdx.x * 256 + threadIdx.x;
  float4 v = *(const float4*)(in + i * 4);
  ushort4 o;
  o.x = f2bf(v.x); o.y = f2bf(v.y); o.z = f2bf(v.z); o.w = f2bf(v.w);
  *(ushort4*)(out + i * 4) = o;
}

// ---------------- kernel 2: left = hyp_w2 @ relu(w1@e+b1) + b2 ----------------
// 2048 blocks x 256 thr (32 waves/CU -> BW-bound stream). h computed per block.
__global__ __launch_bounds__(256) void build_left(
    const float* __restrict__ w1, const float* __restrict__ b1,
    const float* __restrict__ e,
    const float* __restrict__ hyp_w2, const float* __restrict__ hyp_b2,
    float* __restrict__ left) {
  __shared__ float hs[HYP_HID];
  const int tid = threadIdx.x;
  if (tid < HYP_HID) {
    const float4* wr = (const float4*)(w1 + tid * N_ARCH);
    float s = b1[tid];
#pragma unroll
    for (int c = 0; c < 4; c++) {
      float4 wv = wr[c];
      float4 ev = *(const float4*)(e + c * 4);
      s += wv.x * ev.x + wv.y * ev.y + wv.z * ev.z + wv.w * ev.w;
    }
    hs[tid] = fmaxf(s, 0.0f);
  }
  __syncthreads();

  const int lane = tid & 63;
  const int g = lane >> 3;      // row within 8-row pack
  const int gl = lane & 7;      // lane within group
  float4 hf[4];
#pragma unroll
  for (int c = 0; c < 4; c++) hf[c] = *(const float4*)(&hs[c * 32 + gl * 4]);
  const int wid = blockIdx.x * 4 + (tid >> 6);   // [0, 8192)
  const int row0 = wid * 32;
#pragma unroll
  for (int it = 0; it < 4; it++) {
    const int row = row0 + it * 8 + g;
    const float* rp = hyp_w2 + (size_t)row * HYP_HID;
    float s = 0.f;
#pragma unroll
    for (int c = 0; c < 4; c++) {
      float4 v = *(const float4*)(rp + c * 32 + gl * 4);
      s += v.x * hf[c].x + v.y * hf[c].y + v.z * hf[c].z + v.w * hf[c].w;
    }
    s += __shfl_xor(s, 4);
    s += __shfl_xor(s, 2);
    s += __shfl_xor(s, 1);
    if (gl == 0) left[row] = s + hyp_b2[row];
  }
}

// ---------------- kernel 3: W (bf16) = base + left @ lr ----------------
__global__ __launch_bounds__(256) void build_w(
    const float* __restrict__ left, const float* __restrict__ base_w,
    const float* __restrict__ lrf, unsigned short* __restrict__ Wbf) {
  __shared__ float lefts[8 * LOW_RANK];
  const int tid = threadIdx.x;
  const int o0 = blockIdx.x * 8;
#pragma unroll
  for (int i = tid; i < 8 * LOW_RANK; i += 256)
    lefts[i] = left[o0 * LOW_RANK + i];
  __syncthreads();

#pragma unroll
  for (int kk = 0; kk < 4; kk++) {
    const int k = kk * 256 + tid;
    float acc[8];
#pragma unroll
    for (int oi = 0; oi < 8; oi++) acc[oi] = base_w[(size_t)(o0 + oi) * MAX_IN + k];
    for (int r = 0; r < LOW_RANK; r++) {
      float lv = lrf[r * MAX_IN + k];
#pragma unroll
      for (int oi = 0; oi < 8; oi++) acc[oi] += lefts[oi * LOW_RANK + r] * lv;
    }
#pragma unroll
    for (int oi = 0; oi < 8; oi++)
      Wbf[(size_t)(o0 + oi) * MAX_IN + k] = f2bf(acc[oi]);
  }
}

// ---------------- kernel 4: persistent phase-split GEMM ----------------
// grid 256 = 1 block/CU. Each block: two N-adjacent 256x256 tiles (same bm ->
// A panel L2-warm for tile 2). R8's verified 4-phase loop body per tile.
// Between tiles: epilogue stores issue -> restage prologue -> vmcnt(4)+barrier
// (t=NT-1 phase-3 collective barrier already fences all LDS reads).
__global__ __launch_bounds__(512, 2) void gemm_kernel(
    const unsigned short* __restrict__ A,   // [M][K] bf16
    const unsigned short* __restrict__ B,   // [N][K] bf16 (= W)
    const float* __restrict__ bias,         // [N]
    float* __restrict__ C) {                // [M][N] fp32
  constexpr int K = MAX_IN;
  constexpr int N = MAX_OUT;
  constexpr int SLOT = 32768;              // ushorts per slot (A 16K + B 16K)
  constexpr int BOFF = 16384;
  constexpr int NT = K / 64;               // 16
  __shared__ __align__(16) unsigned short lds[2 * SLOT];  // 128 KB

  const int tid = threadIdx.x;             // 0..511
  const int lane = tid & 63;
  const int w = tid >> 6;                  // wave 0..7
  const int wm = w >> 2, wn = w & 3;       // 2M x 4N
  const int fl = lane & 15, hi = lane >> 4;

  // XCD map over 256 blocks: xcd gets 8bm x 4pair region
  const int orig = blockIdx.x;
  const int xcd = orig & 7;
  const int mj = orig >> 3;                // 0..31
  const int bm = ((xcd >> 1) * 8 + (mj >> 2)) * 256;    // 32 bm-tiles
  int bn = ((xcd & 1) * 4 + (mj & 3)) * 512;            // 8 pairs of N-tiles

  // staging: thread covers row rid (+64j), LDS chunk-slot tid&7,
  // logical chunk cst = (tid&7) ^ (rid&7)
  const int rid = tid >> 3;
  const int cst = (tid & 7) ^ (rid & 7);
  const unsigned short* Asrc = A + (size_t)(bm + rid) * K + cst * 8;
  const unsigned short* Bsrc = B + (size_t)(bn + rid) * K + cst * 8;

  // fragment read swizzle: r&7 == fl&7 for all frag rows
  const int swk0 = (hi ^ (fl & 7)) * 8;        // kk=0 (chunk hi)
  const int swk1 = ((4 + hi) ^ (fl & 7)) * 8;  // kk=1 (chunk 4+hi)
  const int arow = (wm * 128 + fl) * 64;
  const int brow = (wn * 64 + fl) * 64;

  f32x4 acc[8][4];
#pragma unroll
  for (int m = 0; m < 8; m++)
#pragma unroll
    for (int n = 0; n < 4; n++) acc[m][n] = (f32x4){0.f, 0.f, 0.f, 0.f};

  short8 a[4][2], b0[2][2], b1[2][2];

#define STAGE_A(s, h, kt)                                                      \
  do {                                                                         \
    gload16(Asrc + (size_t)((h) * 128) * K + (kt) * 64,                        \
            &lds[(s) * SLOT + (((h) * 2) * 512 + tid) * 8]);                   \
    gload16(Asrc + (size_t)((h) * 128 + 64) * K + (kt) * 64,                   \
            &lds[(s) * SLOT + (((h) * 2 + 1) * 512 + tid) * 8]);               \
  } while (0)
#define STAGE_B(s, h, kt)                                                      \
  do {                                                                         \
    gload16(Bsrc + (size_t)((h) * 128) * K + (kt) * 64,                        \
            &lds[(s) * SLOT + BOFF + (((h) * 2) * 512 + tid) * 8]);            \
    gload16(Bsrc + (size_t)((h) * 128 + 64) * K + (kt) * 64,                   \
            &lds[(s) * SLOT + BOFF + (((h) * 2 + 1) * 512 + tid) * 8]);        \
  } while (0)
#define LDA(qm)                                                                \
  _Pragma("unroll") for (int m = 0; m < 4; m++) {                              \
    a[m][0] = *(const short8*)&Aslot[arow + (qm) * 4096 + m * 1024 + swk0];    \
    a[m][1] = *(const short8*)&Aslot[arow + (qm) * 4096 + m * 1024 + swk1];    \
  }
#define LDB(dst, qn)                                                           \
  _Pragma("unroll") for (int n = 0; n < 2; n++) {                              \
    dst[n][0] = *(const short8*)&Bslot[brow + (qn) * 2048 + n * 1024 + swk0];  \
    dst[n][1] = *(const short8*)&Bslot[brow + (qn) * 2048 + n * 1024 + swk1];  \
  }
#define MFMA16(qm, qn, bb)                                                     \
  __builtin_amdgcn_s_setprio(1);                                               \
  _Pragma("unroll") for (int m = 0; m < 4; m++)                                \
  _Pragma("unroll") for (int n = 0; n < 2; n++)                                \
  _Pragma("unroll") for (int kk = 0; kk < 2; kk++)                             \
    acc[(qm) * 4 + m][(qn) * 2 + n] = __builtin_amdgcn_mfma_f32_16x16x32_bf16( \
        a[m][kk], bb[n][kk], acc[(qm) * 4 + m][(qn) * 2 + n], 0, 0, 0);        \
  __builtin_amdgcn_s_setprio(0);
#define BAR1() __builtin_amdgcn_s_barrier();                                   \
  asm volatile("s_waitcnt lgkmcnt(0)" ::: "memory");                           \
  __builtin_amdgcn_sched_barrier(0)
#define BAR2() __builtin_amdgcn_s_barrier(); __builtin_amdgcn_sched_barrier(0)
#define PROLOGUE()                                                             \
  do {                                                                         \
    STAGE_A(0, 0, 0); STAGE_A(0, 1, 0);                                        \
    STAGE_B(0, 0, 0); STAGE_B(0, 1, 0);                                        \
    STAGE_B(1, 0, 1); STAGE_B(1, 1, 1);                                        \
    asm volatile("s_waitcnt vmcnt(4)" ::: "memory");                           \
    __builtin_amdgcn_s_barrier();                                              \
    __builtin_amdgcn_sched_barrier(0);                                         \
  } while (0)

  PROLOGUE();

  for (int tile = 0; tile < 2; ++tile) {
    for (int t = 0; t < NT; ++t) {
      const unsigned short* Aslot = &lds[(t & 1) * SLOT];
      const unsigned short* Bslot = Aslot + BOFF;
      // ---- phase 0: (qm0,qn0); stage A-half0(t+1) ----
      LDA(0); LDB(b0, 0);
      if (t + 1 < NT) STAGE_A((t + 1) & 1, 0, t + 1);
      BAR1();
      MFMA16(0, 0, b0);
      BAR2();
      // ---- phase 1: (qm0,qn1); stage A-half1(t+1) ----
      LDB(b1, 1);
      if (t + 1 < NT) STAGE_A((t + 1) & 1, 1, t + 1);
      BAR1();
      MFMA16(0, 1, b1);
      BAR2();
      // ---- phase 2: (qm1,qn1); stage B-half0(t+2) ----
      LDA(1);
      if (t + 2 < NT) STAGE_B(t & 1, 0, t + 2);
      BAR1();
      MFMA16(1, 1, b1);
      BAR2();
      // ---- phase 3: (qm1,qn0); stage B-half1(t+2); vmcnt(4) ----
      if (t + 2 < NT) STAGE_B(t & 1, 1, t + 2);
      __builtin_amdgcn_s_barrier();
      __builtin_amdgcn_sched_barrier(0);
      MFMA16(1, 0, b0);
      if (t + 2 < NT) {
        asm volatile("s_waitcnt vmcnt(4)" ::: "memory");
      } else if (t + 1 < NT) {
        asm volatile("s_waitcnt vmcnt(0)" ::: "memory");
      }
      if (t + 1 < NT) { BAR2(); }
    }

    // ---- epilogue: C/D layout col=lane&15, row=(lane>>4)*4+j ----
    {
      float bv[4];
#pragma unroll
      for (int n = 0; n < 4; n++) bv[n] = bias[bn + wn * 64 + n * 16 + fl];
#pragma unroll
      for (int m = 0; m < 8; m++) {
        const int gr0 = bm + wm * 128 + m * 16 + hi * 4;
#pragma unroll
        for (int n = 0; n < 4; n++) {
          const int gc = bn + wn * 64 + n * 16 + fl;
#pragma unroll
          for (int jj = 0; jj < 4; jj++)
            C[(size_t)(gr0 + jj) * N + gc] = acc[m][n][jj] + bv[n];
        }
      }
    }

    if (tile == 0) {
      // advance to the N-adjacent tile; restage (A L2-warm, same panel)
#pragma unroll
      for (int m = 0; m < 8; m++)
#pragma unroll
        for (int n = 0; n < 4; n++) acc[m][n] = (f32x4){0.f, 0.f, 0.f, 0.f};
      bn += 256;
      Bsrc += (size_t)256 * K;
      PROLOGUE();
    }
  }
#undef STAGE_A
#undef STAGE_B
#undef LDA
#undef LDB
#undef MFMA16
#undef BAR1
#undef BAR2
#undef PROLOGUE
}

// ---------------- launcher ----------------
extern "C" void kernel_launch(void* const* d_in, const int* in_sizes, int n_in,
                              void* d_out, int out_size, void* d_ws, size_t ws_size,
                              hipStream_t stream) {
  const float* x      = (const float*)d_in[0];
  const float* embed  = (const float*)d_in[1];
  const float* base_w = (const float*)d_in[2];
  const float* base_b = (const float*)d_in[3];
  const float* lrf    = (const float*)d_in[4];
  const float* w1     = (const float*)d_in[5];
  const float* b1     = (const float*)d_in[6];
  const float* w2     = (const float*)d_in[7];
  const float* b2     = (const float*)d_in[8];
  float* out = (float*)d_out;

  char* ws = (char*)d_ws;
  unsigned short* Xbf = (unsigned short*)ws;                                   // 16 MB
  size_t off_w = (size_t)BATCH_M * MAX_IN * 2;
  unsigned short* Wbf = (unsigned short*)(ws + off_w);                         // 8 MB
  size_t off_left = off_w + (size_t)MAX_OUT * MAX_IN * 2;
  size_t need = off_left + (size_t)MAX_OUT * LOW_RANK * 4;                     // +1 MB
  // left scratch: ws if it fits, else tail of d_out (gemm overwrites later)
  float* left = (ws_size >= need)
      ? (float*)(ws + off_left)
      : out + ((size_t)BATCH_M * MAX_OUT - (size_t)MAX_OUT * LOW_RANK);

  hipLaunchKernelGGL(convert_x, dim3(BATCH_M * MAX_IN / 1024), dim3(256), 0, stream, x, Xbf);
  hipLaunchKernelGGL(build_left, dim3(MAX_OUT * LOW_RANK / 128), dim3(256), 0, stream,
                     w1, b1, embed, w2, b2, left);
  hipLaunchKernelGGL(build_w, dim3(MAX_OUT / 8), dim3(256), 0, stream,
                     left, base_w, lrf, Wbf);
  hipLaunchKernelGGL(gemm_kernel, dim3(256), dim3(512), 0, stream,
                     Xbf, Wbf, base_b, out);
}